// Round 6
// baseline (284.555 us; speedup 1.0000x reference)
//
#include <hip/hip_runtime.h>
#include <stdint.h>
#include <math.h>

#define E_DIM 1024
#define W_DIM 1024
#define EW 1048576L   // 1024*1024

typedef _Float16 h16;
typedef __attribute__((ext_vector_type(8))) _Float16 h8;
typedef __attribute__((ext_vector_type(4))) float f4;

__device__ __forceinline__ void async_copy16(h16* lds, const h16* g) {
    __builtin_amdgcn_global_load_lds(
        (const __attribute__((address_space(1))) void*)g,
        (__attribute__((address_space(3))) void*)lds, 16, 0, 0);
}

// ---------------------------------------------------------------------------
// prep: z<12 -> transpose-convert x [12][E][W] fp32 -> [12][W][E] fp16;
//       z>=12 -> convert weight (z-12) fp32 -> fp16 into wh[LK|LQ|LV|M].
// ---------------------------------------------------------------------------
__global__ __launch_bounds__(256) void prep(
    const float* __restrict__ x, const float* __restrict__ LK,
    const float* __restrict__ LQ, const float* __restrict__ LV,
    const float* __restrict__ Mw, h16* __restrict__ xt, h16* __restrict__ wh)
{
    __shared__ float Ts[64][65];
    const int z = blockIdx.z;
    const int t = threadIdx.x;
    if (z < 12) {
        const float* src = x + (long)z * EW;   // [e][w]
        h16* dst = xt + (long)z * EW;          // [w][e]
        const int e0 = blockIdx.y * 64, w0 = blockIdx.x * 64;
        const int r = t >> 4, c4 = (t & 15) * 4;
        #pragma unroll
        for (int p = 0; p < 4; ++p) {
            float4 v = *reinterpret_cast<const float4*>(src + (long)(e0 + r + p * 16) * W_DIM + w0 + c4);
            Ts[c4 + 0][r + p * 16] = v.x;
            Ts[c4 + 1][r + p * 16] = v.y;
            Ts[c4 + 2][r + p * 16] = v.z;
            Ts[c4 + 3][r + p * 16] = v.w;
        }
        __syncthreads();
        #pragma unroll
        for (int p = 0; p < 4; ++p) {
            int wr = r + p * 16;
            union { h16 h[4]; uint2 u; } o;
            o.h[0] = (h16)Ts[wr][c4 + 0];
            o.h[1] = (h16)Ts[wr][c4 + 1];
            o.h[2] = (h16)Ts[wr][c4 + 2];
            o.h[3] = (h16)Ts[wr][c4 + 3];
            *reinterpret_cast<uint2*>(dst + (long)(w0 + wr) * E_DIM + e0 + c4) = o.u;
        }
    } else {
        const float* srcs[4] = {LK, LQ, LV, Mw};
        const float* s = srcs[z - 12];
        h16* o = wh + (long)(z - 12) * EW;
        long base = ((long)(blockIdx.y * 16 + blockIdx.x)) * 1024 + t;  // float4 idx
        #pragma unroll
        for (int k = 0; k < 4; ++k) {
            long i = base + k * 256;
            float4 v = reinterpret_cast<const float4*>(s)[i];
            union { h16 h[4]; uint2 u; } u;
            u.h[0] = (h16)v.x; u.h[1] = (h16)v.y; u.h[2] = (h16)v.z; u.h[3] = (h16)v.w;
            reinterpret_cast<uint2*>(o)[i] = u.u;
        }
    }
}

// ---------------------------------------------------------------------------
// Fused projection GEMMs (K, Q, V), z = proj*4 + batch. 128x128, BK=32.
// Double-buffered global_load_lds staging, ONE barrier per K-iter:
// DMA for tile i+1 issued after iter-i barrier, drained by iter-i+1 barrier.
// ---------------------------------------------------------------------------
__global__ __launch_bounds__(256) void gemm_proj3(
    const h16* __restrict__ xh, const h16* __restrict__ Wts,
    h16* __restrict__ KQV)
{
    __shared__ h16 As[2][128 * 32];
    __shared__ h16 Bs[2][128 * 32];

    const int t = threadIdx.x;
    const int wave = t >> 6, lane = t & 63;
    const int quad = lane >> 4, l16 = lane & 15;
    const int m0 = blockIdx.y * 128, n0 = blockIdx.x * 128;
    const int wm = (wave >> 1) * 64, wn = (wave & 1) * 64;

    const int proj = blockIdx.z >> 2, bz = blockIdx.z & 3;
    const h16 *A, *Bt; h16* C;
    if (proj == 0)      { A = xh + bz * EW;       Bt = Wts;          C = KQV + bz * EW; }
    else if (proj == 1) { A = xh + (4 + bz) * EW; Bt = Wts + EW;     C = KQV + (4 + bz) * EW; }
    else                { A = Wts + 2 * EW;       Bt = xh + (8 + bz) * EW; C = KQV + (8 + bz) * EW; }

    const int sr = t >> 2;
    const int sg = (t & 3) * 8;

    f4 acc[4][4] = {};

    // stage k-tile 0 into buf 0
    async_copy16(&As[0][sr * 32 + sg],        A  + (long)(m0 + sr) * E_DIM + sg);
    async_copy16(&As[0][(sr + 64) * 32 + sg], A  + (long)(m0 + sr + 64) * E_DIM + sg);
    async_copy16(&Bs[0][sr * 32 + sg],        Bt + (long)(n0 + sr) * E_DIM + sg);
    async_copy16(&Bs[0][(sr + 64) * 32 + sg], Bt + (long)(n0 + sr + 64) * E_DIM + sg);

    for (int it = 0; it < 32; ++it) {
        __syncthreads();   // drains DMA for buf it&1; prev compute done
        if (it + 1 < 32) {
            int nb = (it + 1) & 1, k0 = (it + 1) * 32;
            async_copy16(&As[nb][sr * 32 + sg],        A  + (long)(m0 + sr) * E_DIM + k0 + sg);
            async_copy16(&As[nb][(sr + 64) * 32 + sg], A  + (long)(m0 + sr + 64) * E_DIM + k0 + sg);
            async_copy16(&Bs[nb][sr * 32 + sg],        Bt + (long)(n0 + sr) * E_DIM + k0 + sg);
            async_copy16(&Bs[nb][(sr + 64) * 32 + sg], Bt + (long)(n0 + sr + 64) * E_DIM + k0 + sg);
        }
        const h16* as = As[it & 1];
        const h16* bs = Bs[it & 1];

        h8 av[4], bv[4];
        #pragma unroll
        for (int i = 0; i < 4; ++i) {
            av[i] = *reinterpret_cast<const h8*>(as + (wm + i * 16 + l16) * 32 + quad * 8);
            bv[i] = *reinterpret_cast<const h8*>(bs + (wn + i * 16 + l16) * 32 + quad * 8);
        }
        #pragma unroll
        for (int mt = 0; mt < 4; ++mt)
            #pragma unroll
            for (int nt = 0; nt < 4; ++nt)
                acc[mt][nt] = __builtin_amdgcn_mfma_f32_16x16x32_f16(av[mt], bv[nt], acc[mt][nt], 0, 0, 0);
    }

    #pragma unroll
    for (int mt = 0; mt < 4; ++mt)
        #pragma unroll
        for (int i = 0; i < 4; ++i) {
            int m = m0 + wm + mt * 16 + quad * 4 + i;
            #pragma unroll
            for (int nt = 0; nt < 4; ++nt)
                C[(long)m * W_DIM + n0 + wn + nt * 16 + l16] = (h16)acc[mt][nt][i];
        }
}

// ---------------------------------------------------------------------------
// Output GEMM, batch-fused: out = M[1024x1024] x Ao[4096x1024]^T (+bias).
// 64x128 tiles -> 512 blocks. Double-buffered DMA, one barrier/iter.
// ---------------------------------------------------------------------------
__global__ __launch_bounds__(256) void gemm_out(
    const h16* __restrict__ A, const h16* __restrict__ Bt,
    float* __restrict__ C, const float* __restrict__ bias)
{
    __shared__ h16 As[2][64 * 32];
    __shared__ h16 Bs[2][128 * 32];

    const int t = threadIdx.x;
    const int wave = t >> 6, lane = t & 63;
    const int quad = lane >> 4, l16 = lane & 15;
    const int m0 = blockIdx.y * 64, n0 = blockIdx.x * 128;
    const int wm = (wave >> 1) * 32, wn = (wave & 1) * 64;

    f4 acc[2][4] = {};

    const int ga_r = t >> 2, ga_c = (t & 3) * 8;

    async_copy16(&As[0][t * 8], A + (long)(m0 + ga_r) * E_DIM + ga_c);
    #pragma unroll
    for (int j = 0; j < 2; ++j) {
        int g = j * 256 + t;
        async_copy16(&Bs[0][g * 8], Bt + (long)(n0 + (g >> 2)) * E_DIM + (g & 3) * 8);
    }

    for (int it = 0; it < 32; ++it) {
        __syncthreads();
        if (it + 1 < 32) {
            int nb = (it + 1) & 1, k0 = (it + 1) * 32;
            async_copy16(&As[nb][t * 8], A + (long)(m0 + ga_r) * E_DIM + k0 + ga_c);
            #pragma unroll
            for (int j = 0; j < 2; ++j) {
                int g = j * 256 + t;
                async_copy16(&Bs[nb][g * 8], Bt + (long)(n0 + (g >> 2)) * E_DIM + k0 + (g & 3) * 8);
            }
        }
        const h16* as = As[it & 1];
        const h16* bs = Bs[it & 1];
        h8 av[2], bv[4];
        #pragma unroll
        for (int mt = 0; mt < 2; ++mt)
            av[mt] = *reinterpret_cast<const h8*>(as + (wm + mt * 16 + l16) * 32 + quad * 8);
        #pragma unroll
        for (int nt = 0; nt < 4; ++nt)
            bv[nt] = *reinterpret_cast<const h8*>(bs + (wn + nt * 16 + l16) * 32 + quad * 8);
        #pragma unroll
        for (int mt = 0; mt < 2; ++mt)
            #pragma unroll
            for (int nt = 0; nt < 4; ++nt)
                acc[mt][nt] = __builtin_amdgcn_mfma_f32_16x16x32_f16(av[mt], bv[nt], acc[mt][nt], 0, 0, 0);
    }

    #pragma unroll
    for (int mt = 0; mt < 2; ++mt)
        #pragma unroll
        for (int i = 0; i < 4; ++i) {
            int m = m0 + wm + mt * 16 + quad * 4 + i;
            float bv_ = bias ? bias[m] : 0.f;
            #pragma unroll
            for (int nt = 0; nt < 4; ++nt) {
                int n = n0 + wn + nt * 16 + l16;   // n = b*1024 + w
                C[(long)(n >> 10) * EW + (long)m * W_DIM + (n & 1023)] = acc[mt][nt][i] + bv_;
            }
        }
}

// ---------------------------------------------------------------------------
// MFMA flash attention (softmax over q), transposed-S orientation.
//  - S^T = MFMA(A=Q-rows, B=K-rows): col = k = lane&15 -> softmax over q is
//    in-lane + 2 shuffles; alpha & l are per-lane SCALARS.
//  - PV: OUT^T[d][k] = MFMA(A=V, B=P) with P^T round-tripped through a
//    per-wave 4.3 KB LDS tile (only LDS in kernel; NO __syncthreads at all).
//  - K/Q/V fragments load directly from global (L1/L2-served, 16B/lane).
//  - q-tile = 128 (2 MFMAs deep per S tile), k = 16 per wave.
// ---------------------------------------------------------------------------
__global__ __launch_bounds__(256) void attn_mfma(
    const h16* __restrict__ Kt, const h16* __restrict__ Qt,
    const h16* __restrict__ V, h16* __restrict__ AoT)
{
    __shared__ h16 Ps[4][16 * 136];   // per-wave P^T tile [k16][q128], pitch 136

    const int t = threadIdx.x, wave = t >> 6, lane = t & 63;
    const int quad = lane >> 4, l16 = lane & 15;
    const int b = blockIdx.y >> 4, h = blockIdx.y & 15;
    const int kt = 15 - blockIdx.x;            // heavy blocks dispatch first
    const int kbase = kt * 64 + wave * 16;     // wave's first k
    const int kcol = kbase + l16;              // this lane's k column

    const h16* Ktb = Kt + (long)b * EW + h * 64;
    const h16* Qtb = Qt + (long)b * EW + h * 64;
    const h16* Vb  = V  + (long)b * EW + (long)(h * 64) * W_DIM;
    h16* Pw = &Ps[wave][0];

    // K as B-operand: B[kk=d][n=k]; lane n=l16 -> row kcol, kk = quad*8+j (+32)
    h8 kb0 = *reinterpret_cast<const h8*>(Ktb + (long)kcol * E_DIM + quad * 8);
    h8 kb1 = *reinterpret_cast<const h8*>(Ktb + (long)kcol * E_DIM + 32 + quad * 8);

    float mrow = -1e30f, lsum = 0.f;
    f4 O[4] = {};

    const int trips = (kbase + 15) / 128 + 1;

    for (int it = 0; it < trips; ++it) {
        const int q0 = it * 128;

        // S^T[q][k]: row q = q0 + nt*16 + quad*4 + i, col k = kcol
        f4 S[8];
        #pragma unroll
        for (int nt = 0; nt < 8; ++nt) {
            const h16* qrow = Qtb + (long)(q0 + nt * 16 + l16) * E_DIM;
            h8 qa0 = *reinterpret_cast<const h8*>(qrow + quad * 8);
            h8 qa1 = *reinterpret_cast<const h8*>(qrow + 32 + quad * 8);
            f4 s = {};
            s = __builtin_amdgcn_mfma_f32_16x16x32_f16(qa0, kb0, s, 0, 0, 0);
            s = __builtin_amdgcn_mfma_f32_16x16x32_f16(qa1, kb1, s, 0, 0, 0);
            S[nt] = s;
        }

        if (it == trips - 1) {   // causal mask: q > k -> -inf (last tile only)
            #pragma unroll
            for (int nt = 0; nt < 8; ++nt)
                #pragma unroll
                for (int i = 0; i < 4; ++i)
                    if (q0 + nt * 16 + quad * 4 + i > kcol) S[nt][i] = -1e30f;
        }

        // online softmax over q: in-lane reduce + cross-quad xor16/xor32
        float mx = -1e30f;
        #pragma unroll
        for (int nt = 0; nt < 8; ++nt)
            #pragma unroll
            for (int i = 0; i < 4; ++i) mx = fmaxf(mx, S[nt][i]);
        mx = fmaxf(mx, __shfl_xor(mx, 16));
        mx = fmaxf(mx, __shfl_xor(mx, 32));
        float nm = fmaxf(mrow, mx);
        float al = __expf(mrow - nm);
        mrow = nm;

        float ts = 0.f;
        #pragma unroll
        for (int nt = 0; nt < 8; ++nt)
            #pragma unroll
            for (int i = 0; i < 4; ++i) {
                float p = __expf(S[nt][i] - nm);
                S[nt][i] = p;
                ts += p;
            }
        ts += __shfl_xor(ts, 16);
        ts += __shfl_xor(ts, 32);
        lsum = lsum * al + ts;
        #pragma unroll
        for (int dt = 0; dt < 4; ++dt)
            #pragma unroll
            for (int i = 0; i < 4; ++i) O[dt][i] *= al;

        // P^T -> per-wave LDS: P_lds[k=l16][q], 4-half packed writes
        #pragma unroll
        for (int nt = 0; nt < 8; ++nt) {
            union { h16 hh[4]; uint2 u2; } p;
            p.hh[0] = (h16)S[nt][0]; p.hh[1] = (h16)S[nt][1];
            p.hh[2] = (h16)S[nt][2]; p.hh[3] = (h16)S[nt][3];
            *reinterpret_cast<uint2*>(Pw + l16 * 136 + nt * 16 + quad * 4) = p.u2;
        }
        asm volatile("" ::: "memory");   // DS in-order per wave; read after write

        // OUT^T[d][k] += V[d][q] * P[q][k]
        #pragma unroll
        for (int c = 0; c < 4; ++c) {
            h8 pb = *reinterpret_cast<const h8*>(Pw + l16 * 136 + c * 32 + quad * 8);
            #pragma unroll
            for (int dt = 0; dt < 4; ++dt) {
                h8 va = *reinterpret_cast<const h8*>(Vb + (long)(dt * 16 + l16) * W_DIM + q0 + c * 32 + quad * 8);
                O[dt] = __builtin_amdgcn_mfma_f32_16x16x32_f16(va, pb, O[dt], 0, 0, 0);
            }
        }
    }

    // epilogue: transpose O (cols k=l16, rows d) through Pw, store rows of AoT
    float inv = 0.03125f / lsum;
    #pragma unroll
    for (int dt = 0; dt < 4; ++dt) {
        union { h16 hh[4]; uint2 u2; } p;
        #pragma unroll
        for (int i = 0; i < 4; ++i) p.hh[i] = (h16)(O[dt][i] * inv);
        *reinterpret_cast<uint2*>(Pw + l16 * 136 + dt * 16 + quad * 4) = p.u2;
    }
    asm volatile("" ::: "memory");
    #pragma unroll
    for (int j = 0; j < 2; ++j) {
        uint4 vv = *reinterpret_cast<const uint4*>(Pw + l16 * 136 + quad * 16 + j * 8);
        *reinterpret_cast<uint4*>(AoT + (long)b * EW + (long)(kbase + l16) * E_DIM
                                  + h * 64 + quad * 16 + j * 8) = vv;
    }
}

// ---------------------------------------------------------------------------
extern "C" void kernel_launch(void* const* d_in, const int* in_sizes, int n_in,
                              void* d_out, int out_size, void* d_ws, size_t ws_size,
                              hipStream_t stream)
{
    const float* x  = (const float*)d_in[0];  // [3][B][E][W]; x[0]->K, x[1]->Q, x[2]->V
    const float* LQ = (const float*)d_in[1];
    const float* LK = (const float*)d_in[2];
    const float* LV = (const float*)d_in[3];
    const float* Mw = (const float*)d_in[4];
    const float* bb = (const float*)d_in[5];
    float* out = (float*)d_out;
    h16* ws = (h16*)d_ws;

    h16* xh  = ws;                    // [12][W][E] transposed x
    h16* LKh = ws + 12 * EW;          // weights [LK|LQ|LV|M]
    h16* Mh  = ws + 15 * EW;
    h16* Kp  = ws + 16 * EW;          // [B][W][E] (K^T)
    h16* Qp  = ws + 20 * EW;          // [B][W][E] (Q^T)
    h16* Vp  = ws + 24 * EW;          // [B][E][W] (V)
    h16* Ao  = ws + 28 * EW;          // [B][W][E] (attn out^T) = [4096][1024]

    dim3 blk(256);
    prep<<<dim3(16, 16, 16), blk, 0, stream>>>(x, LK, LQ, LV, Mw, xh, LKh);
    gemm_proj3<<<dim3(8, 8, 12), blk, 0, stream>>>(xh, LKh, Kp);
    attn_mfma<<<dim3(16, 64), blk, 0, stream>>>(Kp, Qp, Vp, Ao);
    gemm_out<<<dim3(32, 16), blk, 0, stream>>>(Mh, Ao, out, bb);
}

// Round 7
// 207.352 us; speedup vs baseline: 1.3723x; 1.3723x over previous
//
#include <hip/hip_runtime.h>
#include <stdint.h>
#include <math.h>

#define E_DIM 1024
#define W_DIM 1024
#define EW 1048576L   // 1024*1024

typedef _Float16 h16;
typedef __attribute__((ext_vector_type(8))) _Float16 h8;
typedef __attribute__((ext_vector_type(4))) float f4;

__device__ __forceinline__ void async_copy16(h16* lds, const h16* g) {
    __builtin_amdgcn_global_load_lds(
        (const __attribute__((address_space(1))) void*)g,
        (__attribute__((address_space(3))) void*)lds, 16, 0, 0);
}

// ---------------------------------------------------------------------------
// prep: z<12 -> transpose-convert x [12][E][W] fp32 -> [12][W][E] fp16;
//       z>=12 -> convert weight (z-12) fp32 -> fp16 into wh[LK|LQ|LV|M].
// ---------------------------------------------------------------------------
__global__ __launch_bounds__(256) void prep(
    const float* __restrict__ x, const float* __restrict__ LK,
    const float* __restrict__ LQ, const float* __restrict__ LV,
    const float* __restrict__ Mw, h16* __restrict__ xt, h16* __restrict__ wh)
{
    __shared__ float Ts[64][65];
    const int z = blockIdx.z;
    const int t = threadIdx.x;
    if (z < 12) {
        const float* src = x + (long)z * EW;   // [e][w]
        h16* dst = xt + (long)z * EW;          // [w][e]
        const int e0 = blockIdx.y * 64, w0 = blockIdx.x * 64;
        const int r = t >> 4, c4 = (t & 15) * 4;
        #pragma unroll
        for (int p = 0; p < 4; ++p) {
            float4 v = *reinterpret_cast<const float4*>(src + (long)(e0 + r + p * 16) * W_DIM + w0 + c4);
            Ts[c4 + 0][r + p * 16] = v.x;
            Ts[c4 + 1][r + p * 16] = v.y;
            Ts[c4 + 2][r + p * 16] = v.z;
            Ts[c4 + 3][r + p * 16] = v.w;
        }
        __syncthreads();
        #pragma unroll
        for (int p = 0; p < 4; ++p) {
            int wr = r + p * 16;
            union { h16 h[4]; uint2 u; } o;
            o.h[0] = (h16)Ts[wr][c4 + 0];
            o.h[1] = (h16)Ts[wr][c4 + 1];
            o.h[2] = (h16)Ts[wr][c4 + 2];
            o.h[3] = (h16)Ts[wr][c4 + 3];
            *reinterpret_cast<uint2*>(dst + (long)(w0 + wr) * E_DIM + e0 + c4) = o.u;
        }
    } else {
        const float* srcs[4] = {LK, LQ, LV, Mw};
        const float* s = srcs[z - 12];
        h16* o = wh + (long)(z - 12) * EW;
        long base = ((long)(blockIdx.y * 16 + blockIdx.x)) * 1024 + t;  // float4 idx
        #pragma unroll
        for (int k = 0; k < 4; ++k) {
            long i = base + k * 256;
            float4 v = reinterpret_cast<const float4*>(s)[i];
            union { h16 h[4]; uint2 u; } u;
            u.h[0] = (h16)v.x; u.h[1] = (h16)v.y; u.h[2] = (h16)v.z; u.h[3] = (h16)v.w;
            reinterpret_cast<uint2*>(o)[i] = u.u;
        }
    }
}

// ---------------------------------------------------------------------------
// Fused projection GEMMs (K, Q, V), z = proj*4 + batch. 128x128 tile,
// BK=64, m97-style single-buffer 2-barrier K-loop (32 MFMAs/barrier),
// XOR-swizzled granules: DMA-legal + conflict-free b128 fragment reads.
// ---------------------------------------------------------------------------
__global__ __launch_bounds__(256) void gemm_proj3(
    const h16* __restrict__ xh, const h16* __restrict__ Wts,
    h16* __restrict__ KQV)
{
    __shared__ h16 As[128 * 64];   // granule (row*8 + (cg^(row&7))), 16B each
    __shared__ h16 Bs[128 * 64];

    const int t = threadIdx.x;
    const int wave = t >> 6, lane = t & 63;
    const int quad = lane >> 4, l16 = lane & 15;
    const int m0 = blockIdx.y * 128, n0 = blockIdx.x * 128;
    const int wm = (wave >> 1) * 64, wn = (wave & 1) * 64;

    const int proj = blockIdx.z >> 2, bz = blockIdx.z & 3;
    const h16 *A, *Bt; h16* C;
    if (proj == 0)      { A = xh + bz * EW;       Bt = Wts;          C = KQV + bz * EW; }
    else if (proj == 1) { A = xh + (4 + bz) * EW; Bt = Wts + EW;     C = KQV + (4 + bz) * EW; }
    else                { A = Wts + 2 * EW;       Bt = xh + (8 + bz) * EW; C = KQV + (8 + bz) * EW; }

    f4 acc[4][4] = {};

    for (int k0 = 0; k0 < 1024; k0 += 64) {
        __syncthreads();   // prev iter's fragment reads complete
        #pragma unroll
        for (int j = 0; j < 4; ++j) {
            int g = j * 256 + t, row = g >> 3, cg = (g & 7) ^ (row & 7);
            async_copy16(&As[g * 8], A  + (long)(m0 + row) * E_DIM + k0 + cg * 8);
            async_copy16(&Bs[g * 8], Bt + (long)(n0 + row) * E_DIM + k0 + cg * 8);
        }
        __syncthreads();   // DMA drained by barrier's vmcnt(0)

        h8 av[4][2], bv[4][2];
        #pragma unroll
        for (int i = 0; i < 4; ++i) {
            int ra = wm + i * 16 + l16, rb = wn + i * 16 + l16;
            #pragma unroll
            for (int c = 0; c < 2; ++c) {
                av[i][c] = *reinterpret_cast<const h8*>(&As[(ra * 8 + ((c * 4 + quad) ^ (l16 & 7))) * 8]);
                bv[i][c] = *reinterpret_cast<const h8*>(&Bs[(rb * 8 + ((c * 4 + quad) ^ (l16 & 7))) * 8]);
            }
        }
        #pragma unroll
        for (int c = 0; c < 2; ++c)
            #pragma unroll
            for (int mt = 0; mt < 4; ++mt)
                #pragma unroll
                for (int nt = 0; nt < 4; ++nt)
                    acc[mt][nt] = __builtin_amdgcn_mfma_f32_16x16x32_f16(av[mt][c], bv[nt][c], acc[mt][nt], 0, 0, 0);
    }

    #pragma unroll
    for (int mt = 0; mt < 4; ++mt)
        #pragma unroll
        for (int i = 0; i < 4; ++i) {
            int m = m0 + wm + mt * 16 + quad * 4 + i;
            #pragma unroll
            for (int nt = 0; nt < 4; ++nt)
                C[(long)m * W_DIM + n0 + wn + nt * 16 + l16] = (h16)acc[mt][nt][i];
        }
}

// ---------------------------------------------------------------------------
// Output GEMM, batch-fused: out = M[1024x1024] x Ao[4096x1024]^T (+bias).
// 64x128 tiles -> 512 blocks. BK=64 single-buffer + XOR swizzle.
// ---------------------------------------------------------------------------
__global__ __launch_bounds__(256) void gemm_out(
    const h16* __restrict__ A, const h16* __restrict__ Bt,
    float* __restrict__ C, const float* __restrict__ bias)
{
    __shared__ h16 As[64 * 64];
    __shared__ h16 Bs[128 * 64];

    const int t = threadIdx.x;
    const int wave = t >> 6, lane = t & 63;
    const int quad = lane >> 4, l16 = lane & 15;
    const int m0 = blockIdx.y * 64, n0 = blockIdx.x * 128;
    const int wm = (wave >> 1) * 32, wn = (wave & 1) * 64;

    f4 acc[2][4] = {};

    for (int k0 = 0; k0 < 1024; k0 += 64) {
        __syncthreads();
        #pragma unroll
        for (int j = 0; j < 2; ++j) {
            int g = j * 256 + t, row = g >> 3, cg = (g & 7) ^ (row & 7);
            async_copy16(&As[g * 8], A + (long)(m0 + row) * E_DIM + k0 + cg * 8);
        }
        #pragma unroll
        for (int j = 0; j < 4; ++j) {
            int g = j * 256 + t, row = g >> 3, cg = (g & 7) ^ (row & 7);
            async_copy16(&Bs[g * 8], Bt + (long)(n0 + row) * E_DIM + k0 + cg * 8);
        }
        __syncthreads();

        h8 av[2][2], bv[4][2];
        #pragma unroll
        for (int c = 0; c < 2; ++c) {
            #pragma unroll
            for (int mt = 0; mt < 2; ++mt) {
                int r = wm + mt * 16 + l16;
                av[mt][c] = *reinterpret_cast<const h8*>(&As[(r * 8 + ((c * 4 + quad) ^ (l16 & 7))) * 8]);
            }
            #pragma unroll
            for (int nt = 0; nt < 4; ++nt) {
                int r = wn + nt * 16 + l16;
                bv[nt][c] = *reinterpret_cast<const h8*>(&Bs[(r * 8 + ((c * 4 + quad) ^ (l16 & 7))) * 8]);
            }
        }
        #pragma unroll
        for (int c = 0; c < 2; ++c)
            #pragma unroll
            for (int mt = 0; mt < 2; ++mt)
                #pragma unroll
                for (int nt = 0; nt < 4; ++nt)
                    acc[mt][nt] = __builtin_amdgcn_mfma_f32_16x16x32_f16(av[mt][c], bv[nt][c], acc[mt][nt], 0, 0, 0);
    }

    #pragma unroll
    for (int mt = 0; mt < 2; ++mt)
        #pragma unroll
        for (int i = 0; i < 4; ++i) {
            int m = m0 + wm + mt * 16 + quad * 4 + i;
            float bv_ = bias ? bias[m] : 0.f;
            #pragma unroll
            for (int nt = 0; nt < 4; ++nt) {
                int n = n0 + wn + nt * 16 + l16;   // n = b*1024 + w
                C[(long)(n >> 10) * EW + (long)m * W_DIM + (n & 1023)] = acc[mt][nt][i] + bv_;
            }
        }
}

// ---------------------------------------------------------------------------
// MFMA flash attention (softmax over q), hybrid:
//  - Q/V tiles DMA-staged, double-buffered, ONE barrier/iter (loads overlap)
//  - transposed-S: S^T = MFMA(A=Q-rows, B=K-regs) -> col = k = lane&15 ->
//    softmax over q in-lane + 2 shuffles; alpha & l are per-lane scalars
//  - P^T per-wave LDS round trip (no barrier); K in registers (2 loads/blk)
//  - XOR-swizzled tiles: DMA-legal + conflict-free b128 fragment reads
// ---------------------------------------------------------------------------
__global__ __launch_bounds__(256) void attn_mfma(
    const h16* __restrict__ Kt, const h16* __restrict__ Qt,
    const h16* __restrict__ V, h16* __restrict__ AoT)
{
    __shared__ h16 Qs[2][64 * 64];   // [q][d] swizzled granules
    __shared__ h16 Vs[2][64 * 64];   // [d][q] swizzled granules
    __shared__ h16 Ps[4][16 * 72];   // per-wave P^T tile [k16][q64], pitch 72

    const int t = threadIdx.x, wave = t >> 6, lane = t & 63;
    const int quad = lane >> 4, l16 = lane & 15;
    const int b = blockIdx.y >> 4, h = blockIdx.y & 15;
    const int kt = 15 - blockIdx.x;            // heavy blocks dispatch first
    const int kbase = kt * 64 + wave * 16;     // wave's first k
    const int kcol = kbase + l16;              // this lane's k column

    const h16* Ktb = Kt + (long)b * EW + h * 64;
    const h16* Qtb = Qt + (long)b * EW + h * 64;
    const h16* Vb  = V  + (long)b * EW + (long)(h * 64) * W_DIM;
    h16* Pw = &Ps[wave][0];

    // K as B-operand: lane n=l16 -> row kcol, kk = c*32 + quad*8 + j
    h8 kb0 = *reinterpret_cast<const h8*>(Ktb + (long)kcol * E_DIM + quad * 8);
    h8 kb1 = *reinterpret_cast<const h8*>(Ktb + (long)kcol * E_DIM + 32 + quad * 8);

    // stage tile 0 into buf 0
    #pragma unroll
    for (int j = 0; j < 2; ++j) {
        int g = j * 256 + t, row = g >> 3, cg = (g & 7) ^ (row & 7);
        async_copy16(&Qs[0][g * 8], Qtb + (long)row * E_DIM + cg * 8);
        async_copy16(&Vs[0][g * 8], Vb + (long)row * W_DIM + cg * 8);
    }

    float mrow = -1e30f, lsum = 0.f;
    f4 O[4] = {};

    for (int it = 0; it <= kt; ++it) {
        const int q0 = it * 64;
        __syncthreads();   // drains DMA for buf it&1; prev iter's readers done
        if (it < kt) {
            int nb = (it + 1) & 1, q1 = q0 + 64;
            #pragma unroll
            for (int j = 0; j < 2; ++j) {
                int g = j * 256 + t, row = g >> 3, cg = (g & 7) ^ (row & 7);
                async_copy16(&Qs[nb][g * 8], Qtb + (long)(q1 + row) * E_DIM + cg * 8);
                async_copy16(&Vs[nb][g * 8], Vb + (long)row * W_DIM + q1 + cg * 8);
            }
        }
        const h16* qs = Qs[it & 1];
        const h16* vs = Vs[it & 1];

        // S^T[q][k]: row q = q0+nt*16+quad*4+i, col k = kcol
        f4 S[4];
        #pragma unroll
        for (int nt = 0; nt < 4; ++nt) {
            int row = nt * 16 + l16;
            h8 a0 = *reinterpret_cast<const h8*>(&qs[(row * 8 + (quad ^ (l16 & 7))) * 8]);
            h8 a1 = *reinterpret_cast<const h8*>(&qs[(row * 8 + ((4 + quad) ^ (l16 & 7))) * 8]);
            f4 s = {};
            s = __builtin_amdgcn_mfma_f32_16x16x32_f16(a0, kb0, s, 0, 0, 0);
            s = __builtin_amdgcn_mfma_f32_16x16x32_f16(a1, kb1, s, 0, 0, 0);
            S[nt] = s;
        }

        if (it == kt) {   // diagonal tile: mask q > k
            #pragma unroll
            for (int nt = 0; nt < 4; ++nt)
                #pragma unroll
                for (int i = 0; i < 4; ++i)
                    if (q0 + nt * 16 + quad * 4 + i > kcol) S[nt][i] = -1e30f;
        }

        // online softmax over q: in-lane + cross-quad xor16/xor32
        float mx = -1e30f;
        #pragma unroll
        for (int nt = 0; nt < 4; ++nt)
            #pragma unroll
            for (int i = 0; i < 4; ++i) mx = fmaxf(mx, S[nt][i]);
        mx = fmaxf(mx, __shfl_xor(mx, 16));
        mx = fmaxf(mx, __shfl_xor(mx, 32));
        float nm = fmaxf(mrow, mx);
        float al = __expf(mrow - nm);
        mrow = nm;

        float ts = 0.f;
        #pragma unroll
        for (int nt = 0; nt < 4; ++nt)
            #pragma unroll
            for (int i = 0; i < 4; ++i) {
                float p = __expf(S[nt][i] - nm);
                S[nt][i] = p;
                ts += p;
            }
        ts += __shfl_xor(ts, 16);
        ts += __shfl_xor(ts, 32);
        lsum = lsum * al + ts;
        #pragma unroll
        for (int dt = 0; dt < 4; ++dt)
            #pragma unroll
            for (int i = 0; i < 4; ++i) O[dt][i] *= al;

        // P^T -> per-wave LDS: Pw[k=l16][q], packed b64 writes
        #pragma unroll
        for (int nt = 0; nt < 4; ++nt) {
            union { h16 hh[4]; uint2 u2; } p;
            p.hh[0] = (h16)S[nt][0]; p.hh[1] = (h16)S[nt][1];
            p.hh[2] = (h16)S[nt][2]; p.hh[3] = (h16)S[nt][3];
            *reinterpret_cast<uint2*>(Pw + l16 * 72 + nt * 16 + quad * 4) = p.u2;
        }
        asm volatile("" ::: "memory");   // DS in-order per wave; read after write

        // OUT^T[d][k] += V[d][q] * P[q][k]
        #pragma unroll
        for (int c = 0; c < 2; ++c) {
            h8 pb = *reinterpret_cast<const h8*>(Pw + l16 * 72 + c * 32 + quad * 8);
            #pragma unroll
            for (int dt = 0; dt < 4; ++dt) {
                int r = dt * 16 + l16;
                h8 va = *reinterpret_cast<const h8*>(&vs[(r * 8 + ((c * 4 + quad) ^ (l16 & 7))) * 8]);
                O[dt] = __builtin_amdgcn_mfma_f32_16x16x32_f16(va, pb, O[dt], 0, 0, 0);
            }
        }
    }

    // epilogue: O cols k=l16, rows d -> transpose via Pw, store rows of AoT
    float inv = 0.03125f / lsum;
    #pragma unroll
    for (int dt = 0; dt < 4; ++dt) {
        union { h16 hh[4]; uint2 u2; } p;
        #pragma unroll
        for (int i = 0; i < 4; ++i) p.hh[i] = (h16)(O[dt][i] * inv);
        *reinterpret_cast<uint2*>(Pw + l16 * 72 + dt * 16 + quad * 4) = p.u2;
    }
    asm volatile("" ::: "memory");
    #pragma unroll
    for (int j = 0; j < 2; ++j) {
        uint4 vv = *reinterpret_cast<const uint4*>(Pw + l16 * 72 + quad * 16 + j * 8);
        *reinterpret_cast<uint4*>(AoT + (long)b * EW + (long)(kbase + l16) * E_DIM
                                  + h * 64 + quad * 16 + j * 8) = vv;
    }
}

// ---------------------------------------------------------------------------
extern "C" void kernel_launch(void* const* d_in, const int* in_sizes, int n_in,
                              void* d_out, int out_size, void* d_ws, size_t ws_size,
                              hipStream_t stream)
{
    const float* x  = (const float*)d_in[0];  // [3][B][E][W]; x[0]->K, x[1]->Q, x[2]->V
    const float* LQ = (const float*)d_in[1];
    const float* LK = (const float*)d_in[2];
    const float* LV = (const float*)d_in[3];
    const float* Mw = (const float*)d_in[4];
    const float* bb = (const float*)d_in[5];
    float* out = (float*)d_out;
    h16* ws = (h16*)d_ws;

    h16* xh  = ws;                    // [12][W][E] transposed x
    h16* LKh = ws + 12 * EW;          // weights [LK|LQ|LV|M]
    h16* Mh  = ws + 15 * EW;
    h16* Kp  = ws + 16 * EW;          // [B][W][E] (K^T)
    h16* Qp  = ws + 20 * EW;          // [B][W][E] (Q^T)
    h16* Vp  = ws + 24 * EW;          // [B][E][W] (V)
    h16* Ao  = ws + 28 * EW;          // [B][W][E] (attn out^T) = [4096][1024]

    dim3 blk(256);
    prep<<<dim3(16, 16, 16), blk, 0, stream>>>(x, LK, LQ, LV, Mw, xh, LKh);
    gemm_proj3<<<dim3(8, 8, 12), blk, 0, stream>>>(xh, LKh, Kp);
    attn_mfma<<<dim3(16, 64), blk, 0, stream>>>(Kp, Qp, Vp, Ao);
    gemm_out<<<dim3(32, 16), blk, 0, stream>>>(Mh, Ao, out, bb);
}